// Round 1
// baseline (7003.525 us; speedup 1.0000x reference)
//
#include <hip/hip_runtime.h>

static __device__ __forceinline__ float lrelu(float x){ return x > 0.f ? x : 0.01f*x; }

// ---------------- degree / normalization ----------------
__global__ __launch_bounds__(256) void k_deg_init(float* __restrict__ deg, int n){
  int i = blockIdx.x*256 + threadIdx.x;
  if (i < n) deg[i] = 1.0f;                    // self-loop
}
__global__ __launch_bounds__(256) void k_deg_edges(const int* __restrict__ dst, float* __restrict__ deg, int E){
  int e = blockIdx.x*256 + threadIdx.x;
  if (e < E) atomicAdd(&deg[dst[e]], 1.0f);
}
__global__ __launch_bounds__(256) void k_dis(const float* __restrict__ deg, float* __restrict__ dis, int n){
  int i = blockIdx.x*256 + threadIdx.x;
  if (i < n) dis[i] = rsqrtf(deg[i]);
}

// ---------------- encoder helpers ----------------
// 768 -> 4*CP tiled GEMM phase. xt is [k][row] (col-major, 65 stride => conflict-free
// compute reads), wt[k][col] broadcast reads (col wave-uniform).
template<int CP>
__device__ __forceinline__ void enc_phase768(
    const float* __restrict__ X, const float* __restrict__ W, const float* __restrict__ b,
    float (*xt)[65], float (*wt)[40], float (*xcat)[132],
    int col_off, int row0, int n, int tid)
{
  const int r = tid & 63, cg = tid >> 6;
  const int NC = CP*4;
  float acc[CP];
  #pragma unroll
  for (int j=0;j<CP;++j) acc[j]=0.f;
  for (int kt=0; kt<12; ++kt){
    __syncthreads();
    #pragma unroll
    for (int it=0; it<4; ++it){                 // stage 64 rows x 64 k, transposed
      int f = tid + it*256;
      int rr = f >> 4, k4 = f & 15;
      float4 v = make_float4(0.f,0.f,0.f,0.f);
      if (row0 + rr < n) v = *(const float4*)(X + (size_t)(row0+rr)*768 + kt*64 + k4*4);
      xt[k4*4+0][rr]=v.x; xt[k4*4+1][rr]=v.y; xt[k4*4+2][rr]=v.z; xt[k4*4+3][rr]=v.w;
    }
    for (int idx = tid; idx < 64*NC; idx += 256){
      int k = idx / NC, j = idx % NC;
      wt[k][j] = W[(size_t)(kt*64+k)*NC + j];
    }
    __syncthreads();
    #pragma unroll 8
    for (int k=0;k<64;++k){
      float xv = xt[k][r];
      #pragma unroll
      for (int j=0;j<CP;++j) acc[j] += xv * wt[k][cg*CP + j];
    }
  }
  #pragma unroll
  for (int j=0;j<CP;++j){
    int c = cg*CP + j;
    xcat[r][col_off + c] = lrelu(acc[j] + b[c]);
  }
}

// small-K encoder (num/cat/nf): direct global reads (tiny inputs, L1/L2 resident)
template<int K, int CP>
__device__ __forceinline__ void enc_small(
    const float* __restrict__ X, const float* __restrict__ W, const float* __restrict__ b,
    float (*xcat)[132], int col_off, int row0, int n, int tid)
{
  const int r = tid & 63, cg = tid >> 6;
  const int NC = CP*4;
  float xr[K];
  #pragma unroll
  for (int k=0;k<K;++k) xr[k] = (row0 + r < n) ? X[(size_t)(row0+r)*K + k] : 0.f;
  #pragma unroll
  for (int j=0;j<CP;++j){
    int c = cg*CP + j;
    float a = b[c];
    #pragma unroll
    for (int k=0;k<K;++k) a += xr[k]*W[k*NC + c];
    xcat[r][col_off + c] = lrelu(a);
  }
}

// encoders + concat + W_in linear + lrelu, fused: writes x0[N,128]
__global__ __launch_bounds__(256) void k_encoder(
    const float* __restrict__ des, const float* __restrict__ tweet,
    const float* __restrict__ nump, const float* __restrict__ catp,
    const float* __restrict__ nfp,
    const float* __restrict__ Wd, const float* __restrict__ bd,
    const float* __restrict__ Wt, const float* __restrict__ bt,
    const float* __restrict__ Wn, const float* __restrict__ bn,
    const float* __restrict__ Wc, const float* __restrict__ bc,
    const float* __restrict__ Wf, const float* __restrict__ bf_,
    const float* __restrict__ Wi, const float* __restrict__ bi,
    float* __restrict__ x0, int n)
{
  __shared__ float xt[64][65];
  __shared__ float wt[64][40];
  __shared__ float xcat[64][132];
  __shared__ float win[32][128];
  const int tid = threadIdx.x;
  const int row0 = blockIdx.x * 64;

  enc_phase768<7>(des,   Wd, bd, xt, wt, xcat, 0,   row0, n, tid);   // cols 0..27
  enc_phase768<9>(tweet, Wt, bt, xt, wt, xcat, 28,  row0, n, tid);   // cols 28..63
  enc_small<7,3>(nump,  Wn, bn, xcat, 64,  row0, n, tid);            // cols 64..75
  enc_small<11,10>(catp, Wc, bc, xcat, 76, row0, n, tid);            // cols 76..115
  enc_small<1,3>(nfp,   Wf, bf_, xcat, 116, row0, n, tid);           // cols 116..127

  // ---- x = lrelu(xcat @ W_in + b_in)
  const int tc = tid & 15, tr = tid >> 4;
  float a2[4][8];
  #pragma unroll
  for (int r=0;r<4;++r)
    #pragma unroll
    for (int c=0;c<8;++c) a2[r][c]=0.f;

  for (int kt=0; kt<4; ++kt){
    __syncthreads();
    #pragma unroll
    for (int it=0;it<4;++it){
      int f = tid + it*256;
      int rk = f >> 5, c4 = f & 31;
      *(float4*)(&win[rk][c4*4]) = *(const float4*)(Wi + (size_t)(kt*32+rk)*128 + c4*4);
    }
    __syncthreads();
    #pragma unroll 4
    for (int k=0;k<32;++k){
      float av[4];
      #pragma unroll
      for (int rr=0;rr<4;++rr) av[rr] = xcat[tr*4+rr][kt*32+k];
      float4 w0 = *(const float4*)(&win[k][tc*8]);
      float4 w1 = *(const float4*)(&win[k][tc*8+4]);
      #pragma unroll
      for (int rr=0;rr<4;++rr){
        a2[rr][0] += av[rr]*w0.x; a2[rr][1] += av[rr]*w0.y;
        a2[rr][2] += av[rr]*w0.z; a2[rr][3] += av[rr]*w0.w;
        a2[rr][4] += av[rr]*w1.x; a2[rr][5] += av[rr]*w1.y;
        a2[rr][6] += av[rr]*w1.z; a2[rr][7] += av[rr]*w1.w;
      }
    }
  }
  float4 bv0 = *(const float4*)(bi + tc*8);
  float4 bv1 = *(const float4*)(bi + tc*8 + 4);
  #pragma unroll
  for (int rr=0;rr<4;++rr){
    int row = row0 + tr*4 + rr;
    if (row < n){
      float4 o0 = { lrelu(a2[rr][0]+bv0.x), lrelu(a2[rr][1]+bv0.y),
                    lrelu(a2[rr][2]+bv0.z), lrelu(a2[rr][3]+bv0.w) };
      float4 o1 = { lrelu(a2[rr][4]+bv1.x), lrelu(a2[rr][5]+bv1.y),
                    lrelu(a2[rr][6]+bv1.z), lrelu(a2[rr][7]+bv1.w) };
      *(float4*)(x0 + (size_t)row*128 + tc*8)     = o0;
      *(float4*)(x0 + (size_t)row*128 + tc*8 + 4) = o1;
    }
  }
}

// ---------------- generic 128x128 GEMM; FINAL fuses lrelu + (128->2) head ----------------
template<int ACT, int FINAL>
__global__ __launch_bounds__(256) void k_gemm128(
    const float* __restrict__ X, const float* __restrict__ W, const float* __restrict__ bias,
    float* __restrict__ Y, const float* __restrict__ W2, const float* __restrict__ b2, int n)
{
  __shared__ float xs[64][132];
  __shared__ float wt[32][128];
  const int tid = threadIdx.x;
  const int row0 = blockIdx.x * 64;

  #pragma unroll
  for (int it=0; it<8; ++it){
    int f = tid + it*256;
    int r = f >> 5, c4 = f & 31;
    float4 v = make_float4(0.f,0.f,0.f,0.f);
    if (row0 + r < n) v = *(const float4*)(X + (size_t)(row0+r)*128 + c4*4);
    *(float4*)(&xs[r][c4*4]) = v;
  }
  const int tc = tid & 15, tr = tid >> 4;
  float a2[4][8];
  #pragma unroll
  for (int r=0;r<4;++r)
    #pragma unroll
    for (int c=0;c<8;++c) a2[r][c]=0.f;

  for (int kt=0; kt<4; ++kt){
    __syncthreads();
    #pragma unroll
    for (int it=0;it<4;++it){
      int f = tid + it*256;
      int rk = f >> 5, c4 = f & 31;
      *(float4*)(&wt[rk][c4*4]) = *(const float4*)(W + (size_t)(kt*32+rk)*128 + c4*4);
    }
    __syncthreads();
    #pragma unroll 4
    for (int k=0;k<32;++k){
      float av[4];
      #pragma unroll
      for (int rr=0;rr<4;++rr) av[rr] = xs[tr*4+rr][kt*32+k];
      float4 w0 = *(const float4*)(&wt[k][tc*8]);
      float4 w1 = *(const float4*)(&wt[k][tc*8+4]);
      #pragma unroll
      for (int rr=0;rr<4;++rr){
        a2[rr][0] += av[rr]*w0.x; a2[rr][1] += av[rr]*w0.y;
        a2[rr][2] += av[rr]*w0.z; a2[rr][3] += av[rr]*w0.w;
        a2[rr][4] += av[rr]*w1.x; a2[rr][5] += av[rr]*w1.y;
        a2[rr][6] += av[rr]*w1.z; a2[rr][7] += av[rr]*w1.w;
      }
    }
  }

  float vv[4][8];
  #pragma unroll
  for (int rr=0;rr<4;++rr){
    #pragma unroll
    for (int cc=0;cc<8;++cc){
      float v = a2[rr][cc];
      if (ACT) { v += bias[tc*8+cc]; v = lrelu(v); }
      vv[rr][cc] = v;
    }
  }

  if (!FINAL){
    #pragma unroll
    for (int rr=0;rr<4;++rr){
      int row = row0 + tr*4 + rr;
      if (row < n){
        float4 o0 = { vv[rr][0], vv[rr][1], vv[rr][2], vv[rr][3] };
        float4 o1 = { vv[rr][4], vv[rr][5], vv[rr][6], vv[rr][7] };
        *(float4*)(Y + (size_t)row*128 + tc*8)     = o0;
        *(float4*)(Y + (size_t)row*128 + tc*8 + 4) = o1;
      }
    }
  } else {
    __syncthreads();                 // done reading xs as input
    #pragma unroll
    for (int rr=0;rr<4;++rr)
      #pragma unroll
      for (int cc=0;cc<8;++cc) xs[tr*4+rr][tc*8+cc] = vv[rr][cc];
    __syncthreads();
    if (tid < 128){
      int r = tid & 63, j = tid >> 6;
      float a = b2[j];
      #pragma unroll 8
      for (int k=0;k<128;++k) a += xs[r][k]*W2[k*2 + j];
      int row = row0 + r;
      if (row < n) Y[(size_t)row*2 + j] = a;
    }
  }
}

// ---------------- GCN scatter ----------------
__global__ __launch_bounds__(256) void k_scatter_init(
    const float* __restrict__ y, const float* __restrict__ dis,
    const float* __restrict__ bias, float* __restrict__ out, int n)
{
  int idx = blockIdx.x*256 + threadIdx.x;     // n*32 items
  if (idx >= n*32) return;
  int i = idx >> 5, c4 = idx & 31;
  float s = dis[i]*dis[i];                    // self-loop norm = 1/deg
  float4 v = *(const float4*)(y + (size_t)i*128 + c4*4);
  float4 b = *(const float4*)(bias + c4*4);
  float4 o = { v.x*s + b.x, v.y*s + b.y, v.z*s + b.z, v.w*s + b.w };
  *(float4*)(out + (size_t)i*128 + c4*4) = o;
}

__global__ __launch_bounds__(256) void k_scatter_edges(
    const float* __restrict__ y, const float* __restrict__ dis,
    const int* __restrict__ src, const int* __restrict__ dst,
    float* __restrict__ out, int E)
{
  int idx = blockIdx.x*256 + threadIdx.x;     // E*32 items (fits int: 51.2M)
  if (idx >= E*32) return;
  int e = idx >> 5, c4 = idx & 31;
  int s = src[e], d = dst[e];
  float w = dis[s]*dis[d];
  float4 v = *(const float4*)(y + (size_t)s*128 + c4*4);
  float* o = out + (size_t)d*128 + c4*4;
  atomicAdd(o+0, v.x*w); atomicAdd(o+1, v.y*w);
  atomicAdd(o+2, v.z*w); atomicAdd(o+3, v.w*w);
}

extern "C" void kernel_launch(void* const* d_in, const int* in_sizes, int n_in,
                              void* d_out, int out_size, void* d_ws, size_t ws_size,
                              hipStream_t stream)
{
  (void)n_in; (void)out_size; (void)ws_size;
  const float* des   = (const float*)d_in[0];
  const float* tweet = (const float*)d_in[1];
  const float* nump  = (const float*)d_in[2];
  const float* catp  = (const float*)d_in[3];
  const float* nfp   = (const float*)d_in[4];
  const int*   eidx  = (const int*)d_in[5];
  const float* Wd = (const float*)d_in[7];  const float* bd = (const float*)d_in[8];
  const float* Wt = (const float*)d_in[9];  const float* bt = (const float*)d_in[10];
  const float* Wn = (const float*)d_in[11]; const float* bn = (const float*)d_in[12];
  const float* Wc = (const float*)d_in[13]; const float* bc = (const float*)d_in[14];
  const float* Wf = (const float*)d_in[15]; const float* bf_ = (const float*)d_in[16];
  const float* Wi = (const float*)d_in[17]; const float* bi = (const float*)d_in[18];
  const float* Wg1 = (const float*)d_in[19]; const float* bg1 = (const float*)d_in[20];
  const float* Wg2 = (const float*)d_in[21]; const float* bg2 = (const float*)d_in[22];
  const float* Wo1 = (const float*)d_in[23]; const float* bo1 = (const float*)d_in[24];
  const float* Wo2 = (const float*)d_in[25]; const float* bo2 = (const float*)d_in[26];

  const int n = in_sizes[0] / 768;
  const int E = in_sizes[5] / 2;
  const int* srcp = eidx;
  const int* dstp = eidx + E;

  float* ws   = (float*)d_ws;
  float* deg  = ws;
  float* dis  = ws + n;
  float* bufA = ws + 2*(size_t)n;
  float* bufB = bufA + (size_t)n*128;
  float* bufC = bufB + (size_t)n*128;

  const int gb1  = (n + 255)/256;
  const int gbe  = (E + 255)/256;
  const int grow = (n + 63)/64;
  const int gsi  = (n*32 + 255)/256;
  const int gse  = (E*32 + 255)/256;

  k_deg_init <<<gb1, 256, 0, stream>>>(deg, n);
  k_deg_edges<<<gbe, 256, 0, stream>>>(dstp, deg, E);
  k_dis      <<<gb1, 256, 0, stream>>>(deg, dis, n);

  k_encoder<<<grow, 256, 0, stream>>>(des,tweet,nump,catp,nfp,
      Wd,bd, Wt,bt, Wn,bn, Wc,bc, Wf,bf_, Wi,bi, bufA, n);

  // GCN layer 1: y = x0 @ Wg1 ; out = scatter(y)*norm + bg1
  k_gemm128<0,0><<<grow, 256, 0, stream>>>(bufA, Wg1, nullptr, bufB, nullptr, nullptr, n);
  k_scatter_init <<<gsi, 256, 0, stream>>>(bufB, dis, bg1, bufC, n);
  k_scatter_edges<<<gse, 256, 0, stream>>>(bufB, dis, srcp, dstp, bufC, E);

  // GCN layer 2
  k_gemm128<0,0><<<grow, 256, 0, stream>>>(bufC, Wg2, nullptr, bufA, nullptr, nullptr, n);
  k_scatter_init <<<gsi, 256, 0, stream>>>(bufA, dis, bg2, bufB, n);
  k_scatter_edges<<<gse, 256, 0, stream>>>(bufA, dis, srcp, dstp, bufB, E);

  // head: out = (lrelu(x @ Wo1 + bo1)) @ Wo2 + bo2
  k_gemm128<1,1><<<grow, 256, 0, stream>>>(bufB, Wo1, bo1, (float*)d_out, Wo2, bo2, n);
}

// Round 2
// 1912.947 us; speedup vs baseline: 3.6611x; 3.6611x over previous
//
#include <hip/hip_runtime.h>

static __device__ __forceinline__ float lrelu(float x){ return x > 0.f ? x : 0.01f*x; }

// ================= CSR build =================
__global__ __launch_bounds__(256) void k_hist(const int* __restrict__ dst, int* __restrict__ cnt, int E){
  int e = blockIdx.x*256 + threadIdx.x;
  if (e < E) atomicAdd(&cnt[dst[e]], 1);
}

// scan phase 1: each block handles 1024 elems (4/thread serial + block scan of 256 sums)
__global__ __launch_bounds__(256) void k_scan1(const int* __restrict__ cnt, int* __restrict__ rowptr,
                                               int* __restrict__ bsum, int n){
  __shared__ int sh[256];
  const int t = threadIdx.x;
  const int base = blockIdx.x*1024 + t*4;
  int v0 = (base+0<n)? cnt[base+0]:0;
  int v1 = (base+1<n)? cnt[base+1]:0;
  int v2 = (base+2<n)? cnt[base+2]:0;
  int v3 = (base+3<n)? cnt[base+3]:0;
  int s = v0+v1+v2+v3;
  sh[t] = s; __syncthreads();
  #pragma unroll
  for (int off=1; off<256; off<<=1){
    int u = (t>=off)? sh[t-off] : 0;
    __syncthreads();
    sh[t] += u;
    __syncthreads();
  }
  int ex = sh[t] - s;                 // exclusive prefix of this thread's chunk
  if (base+0<n) rowptr[base+0] = ex;
  if (base+1<n) rowptr[base+1] = ex+v0;
  if (base+2<n) rowptr[base+2] = ex+v0+v1;
  if (base+3<n) rowptr[base+3] = ex+v0+v1+v2;
  if (t==255) bsum[blockIdx.x] = sh[255];
}
// scan phase 2: exclusive-scan the block sums (nb <= 256) in one block
__global__ __launch_bounds__(256) void k_scan2(int* __restrict__ bsum, int nb){
  __shared__ int sh[256];
  const int t = threadIdx.x;
  int s = (t<nb)? bsum[t] : 0;
  sh[t] = s; __syncthreads();
  #pragma unroll
  for (int off=1; off<256; off<<=1){
    int u = (t>=off)? sh[t-off] : 0;
    __syncthreads();
    sh[t] += u;
    __syncthreads();
  }
  if (t<nb) bsum[t] = sh[t] - s;
}
// scan phase 3: add block offsets; also deg->dis, cursor init, rowptr[n]=E
__global__ __launch_bounds__(256) void k_scan3(int* __restrict__ rowptr, const int* __restrict__ bsum,
                                               const int* __restrict__ cnt, float* __restrict__ dis,
                                               int* __restrict__ cursor, int n, int E){
  int i = blockIdx.x*256 + threadIdx.x;
  if (i < n){
    int r = rowptr[i] + bsum[i>>10];
    rowptr[i] = r;
    cursor[i] = r;
    dis[i] = rsqrtf((float)cnt[i] + 1.0f);   // +1 self-loop
  }
  if (i==0) rowptr[n] = E;
}
__global__ __launch_bounds__(256) void k_fill(const int* __restrict__ src, const int* __restrict__ dst,
                                              int* __restrict__ cursor, int* __restrict__ csr, int E){
  int e = blockIdx.x*256 + threadIdx.x;
  if (e < E){
    int pos = atomicAdd(&cursor[dst[e]], 1);
    csr[pos] = src[e];
  }
}

// ================= pull aggregation =================
// out[d] = dis[d] * ( y'[d] + sum_{s in N(d)} y'[s] ) + bias,  y' = (x@W)*dis pre-scaled
__global__ __launch_bounds__(256) void k_gather(
    const float* __restrict__ yp, const int* __restrict__ rowptr,
    const int* __restrict__ csr, const float* __restrict__ dis,
    const float* __restrict__ bias, float* __restrict__ out, int n)
{
  int node = blockIdx.x*4 + (threadIdx.x>>6);
  if (node >= n) return;
  const int lane = threadIdx.x & 63;
  float2 acc = *(const float2*)(yp + (size_t)node*128 + lane*2);   // self-loop
  int j = rowptr[node], end = rowptr[node+1];
  for (; j+4<=end; j+=4){
    int s0=csr[j], s1=csr[j+1], s2=csr[j+2], s3=csr[j+3];
    float2 v0 = *(const float2*)(yp + (size_t)s0*128 + lane*2);
    float2 v1 = *(const float2*)(yp + (size_t)s1*128 + lane*2);
    float2 v2 = *(const float2*)(yp + (size_t)s2*128 + lane*2);
    float2 v3 = *(const float2*)(yp + (size_t)s3*128 + lane*2);
    acc.x += (v0.x+v1.x) + (v2.x+v3.x);
    acc.y += (v0.y+v1.y) + (v2.y+v3.y);
  }
  for (; j<end; ++j){
    int s = csr[j];
    float2 v = *(const float2*)(yp + (size_t)s*128 + lane*2);
    acc.x += v.x; acc.y += v.y;
  }
  float dd = dis[node];
  float2 b = *(const float2*)(bias + lane*2);
  float2 o = { acc.x*dd + b.x, acc.y*dd + b.y };
  *(float2*)(out + (size_t)node*128 + lane*2) = o;
}

// ================= encoder helpers =================
template<int CP>
__device__ __forceinline__ void enc_phase768(
    const float* __restrict__ X, const float* __restrict__ W, const float* __restrict__ b,
    float (*xt)[65], float (*wt)[40], float (*xcat)[132],
    int col_off, int row0, int n, int tid)
{
  const int r = tid & 63, cg = tid >> 6;
  const int NC = CP*4;
  float acc[CP];
  #pragma unroll
  for (int j=0;j<CP;++j) acc[j]=0.f;
  for (int kt=0; kt<12; ++kt){
    __syncthreads();
    #pragma unroll
    for (int it=0; it<4; ++it){
      int f = tid + it*256;
      int rr = f >> 4, k4 = f & 15;
      float4 v = make_float4(0.f,0.f,0.f,0.f);
      if (row0 + rr < n) v = *(const float4*)(X + (size_t)(row0+rr)*768 + kt*64 + k4*4);
      xt[k4*4+0][rr]=v.x; xt[k4*4+1][rr]=v.y; xt[k4*4+2][rr]=v.z; xt[k4*4+3][rr]=v.w;
    }
    for (int idx = tid; idx < 64*NC; idx += 256){
      int k = idx / NC, j = idx % NC;
      wt[k][j] = W[(size_t)(kt*64+k)*NC + j];
    }
    __syncthreads();
    #pragma unroll 8
    for (int k=0;k<64;++k){
      float xv = xt[k][r];
      #pragma unroll
      for (int j=0;j<CP;++j) acc[j] += xv * wt[k][cg*CP + j];
    }
  }
  #pragma unroll
  for (int j=0;j<CP;++j){
    int c = cg*CP + j;
    xcat[r][col_off + c] = lrelu(acc[j] + b[c]);
  }
}

template<int K, int CP>
__device__ __forceinline__ void enc_small(
    const float* __restrict__ X, const float* __restrict__ W, const float* __restrict__ b,
    float (*xcat)[132], int col_off, int row0, int n, int tid)
{
  const int r = tid & 63, cg = tid >> 6;
  const int NC = CP*4;
  float xr[K];
  #pragma unroll
  for (int k=0;k<K;++k) xr[k] = (row0 + r < n) ? X[(size_t)(row0+r)*K + k] : 0.f;
  #pragma unroll
  for (int j=0;j<CP;++j){
    int c = cg*CP + j;
    float a = b[c];
    #pragma unroll
    for (int k=0;k<K;++k) a += xr[k]*W[k*NC + c];
    xcat[r][col_off + c] = lrelu(a);
  }
}

__global__ __launch_bounds__(256) void k_encoder(
    const float* __restrict__ des, const float* __restrict__ tweet,
    const float* __restrict__ nump, const float* __restrict__ catp,
    const float* __restrict__ nfp,
    const float* __restrict__ Wd, const float* __restrict__ bd,
    const float* __restrict__ Wt, const float* __restrict__ bt,
    const float* __restrict__ Wn, const float* __restrict__ bn,
    const float* __restrict__ Wc, const float* __restrict__ bc,
    const float* __restrict__ Wf, const float* __restrict__ bf_,
    const float* __restrict__ Wi, const float* __restrict__ bi,
    float* __restrict__ x0, int n)
{
  __shared__ float xt[64][65];
  __shared__ float wt[64][40];
  __shared__ float xcat[64][132];
  __shared__ float win[32][128];
  const int tid = threadIdx.x;
  const int row0 = blockIdx.x * 64;

  enc_phase768<7>(des,   Wd, bd, xt, wt, xcat, 0,   row0, n, tid);
  enc_phase768<9>(tweet, Wt, bt, xt, wt, xcat, 28,  row0, n, tid);
  enc_small<7,3>(nump,  Wn, bn, xcat, 64,  row0, n, tid);
  enc_small<11,10>(catp, Wc, bc, xcat, 76, row0, n, tid);
  enc_small<1,3>(nfp,   Wf, bf_, xcat, 116, row0, n, tid);

  const int tc = tid & 15, tr = tid >> 4;
  float a2[4][8];
  #pragma unroll
  for (int r=0;r<4;++r)
    #pragma unroll
    for (int c=0;c<8;++c) a2[r][c]=0.f;

  for (int kt=0; kt<4; ++kt){
    __syncthreads();
    #pragma unroll
    for (int it=0;it<4;++it){
      int f = tid + it*256;
      int rk = f >> 5, c4 = f & 31;
      *(float4*)(&win[rk][c4*4]) = *(const float4*)(Wi + (size_t)(kt*32+rk)*128 + c4*4);
    }
    __syncthreads();
    #pragma unroll 4
    for (int k=0;k<32;++k){
      float av[4];
      #pragma unroll
      for (int rr=0;rr<4;++rr) av[rr] = xcat[tr*4+rr][kt*32+k];
      float4 w0 = *(const float4*)(&win[k][tc*8]);
      float4 w1 = *(const float4*)(&win[k][tc*8+4]);
      #pragma unroll
      for (int rr=0;rr<4;++rr){
        a2[rr][0] += av[rr]*w0.x; a2[rr][1] += av[rr]*w0.y;
        a2[rr][2] += av[rr]*w0.z; a2[rr][3] += av[rr]*w0.w;
        a2[rr][4] += av[rr]*w1.x; a2[rr][5] += av[rr]*w1.y;
        a2[rr][6] += av[rr]*w1.z; a2[rr][7] += av[rr]*w1.w;
      }
    }
  }
  float4 bv0 = *(const float4*)(bi + tc*8);
  float4 bv1 = *(const float4*)(bi + tc*8 + 4);
  #pragma unroll
  for (int rr=0;rr<4;++rr){
    int row = row0 + tr*4 + rr;
    if (row < n){
      float4 o0 = { lrelu(a2[rr][0]+bv0.x), lrelu(a2[rr][1]+bv0.y),
                    lrelu(a2[rr][2]+bv0.z), lrelu(a2[rr][3]+bv0.w) };
      float4 o1 = { lrelu(a2[rr][4]+bv1.x), lrelu(a2[rr][5]+bv1.y),
                    lrelu(a2[rr][6]+bv1.z), lrelu(a2[rr][7]+bv1.w) };
      *(float4*)(x0 + (size_t)row*128 + tc*8)     = o0;
      *(float4*)(x0 + (size_t)row*128 + tc*8 + 4) = o1;
    }
  }
}

// ================= 128x128 GEMM =================
// SCALE: multiply output row by scale[row] (dis).  FINAL: fuse lrelu + 128->2 head.
template<int ACT, int FINAL, int SCALE>
__global__ __launch_bounds__(256) void k_gemm128(
    const float* __restrict__ X, const float* __restrict__ W, const float* __restrict__ bias,
    float* __restrict__ Y, const float* __restrict__ W2, const float* __restrict__ b2,
    const float* __restrict__ scale, int n)
{
  __shared__ float xs[64][132];
  __shared__ float wt[32][128];
  const int tid = threadIdx.x;
  const int row0 = blockIdx.x * 64;

  #pragma unroll
  for (int it=0; it<8; ++it){
    int f = tid + it*256;
    int r = f >> 5, c4 = f & 31;
    float4 v = make_float4(0.f,0.f,0.f,0.f);
    if (row0 + r < n) v = *(const float4*)(X + (size_t)(row0+r)*128 + c4*4);
    *(float4*)(&xs[r][c4*4]) = v;
  }
  const int tc = tid & 15, tr = tid >> 4;
  float a2[4][8];
  #pragma unroll
  for (int r=0;r<4;++r)
    #pragma unroll
    for (int c=0;c<8;++c) a2[r][c]=0.f;

  for (int kt=0; kt<4; ++kt){
    __syncthreads();
    #pragma unroll
    for (int it=0;it<4;++it){
      int f = tid + it*256;
      int rk = f >> 5, c4 = f & 31;
      *(float4*)(&wt[rk][c4*4]) = *(const float4*)(W + (size_t)(kt*32+rk)*128 + c4*4);
    }
    __syncthreads();
    #pragma unroll 4
    for (int k=0;k<32;++k){
      float av[4];
      #pragma unroll
      for (int rr=0;rr<4;++rr) av[rr] = xs[tr*4+rr][kt*32+k];
      float4 w0 = *(const float4*)(&wt[k][tc*8]);
      float4 w1 = *(const float4*)(&wt[k][tc*8+4]);
      #pragma unroll
      for (int rr=0;rr<4;++rr){
        a2[rr][0] += av[rr]*w0.x; a2[rr][1] += av[rr]*w0.y;
        a2[rr][2] += av[rr]*w0.z; a2[rr][3] += av[rr]*w0.w;
        a2[rr][4] += av[rr]*w1.x; a2[rr][5] += av[rr]*w1.y;
        a2[rr][6] += av[rr]*w1.z; a2[rr][7] += av[rr]*w1.w;
      }
    }
  }

  float vv[4][8];
  #pragma unroll
  for (int rr=0;rr<4;++rr){
    #pragma unroll
    for (int cc=0;cc<8;++cc){
      float v = a2[rr][cc];
      if (ACT) { v += bias[tc*8+cc]; v = lrelu(v); }
      vv[rr][cc] = v;
    }
  }

  if (!FINAL){
    #pragma unroll
    for (int rr=0;rr<4;++rr){
      int row = row0 + tr*4 + rr;
      if (row < n){
        float s = SCALE ? scale[row] : 1.0f;
        float4 o0 = { vv[rr][0]*s, vv[rr][1]*s, vv[rr][2]*s, vv[rr][3]*s };
        float4 o1 = { vv[rr][4]*s, vv[rr][5]*s, vv[rr][6]*s, vv[rr][7]*s };
        *(float4*)(Y + (size_t)row*128 + tc*8)     = o0;
        *(float4*)(Y + (size_t)row*128 + tc*8 + 4) = o1;
      }
    }
  } else {
    __syncthreads();
    #pragma unroll
    for (int rr=0;rr<4;++rr)
      #pragma unroll
      for (int cc=0;cc<8;++cc) xs[tr*4+rr][tc*8+cc] = vv[rr][cc];
    __syncthreads();
    if (tid < 128){
      int r = tid & 63, j = tid >> 6;
      float a = b2[j];
      #pragma unroll 8
      for (int k=0;k<128;++k) a += xs[r][k]*W2[k*2 + j];
      int row = row0 + r;
      if (row < n) Y[(size_t)row*2 + j] = a;
    }
  }
}

extern "C" void kernel_launch(void* const* d_in, const int* in_sizes, int n_in,
                              void* d_out, int out_size, void* d_ws, size_t ws_size,
                              hipStream_t stream)
{
  (void)n_in; (void)out_size; (void)ws_size;
  const float* des   = (const float*)d_in[0];
  const float* tweet = (const float*)d_in[1];
  const float* nump  = (const float*)d_in[2];
  const float* catp  = (const float*)d_in[3];
  const float* nfp   = (const float*)d_in[4];
  const int*   eidx  = (const int*)d_in[5];
  const float* Wd = (const float*)d_in[7];  const float* bd = (const float*)d_in[8];
  const float* Wt = (const float*)d_in[9];  const float* bt = (const float*)d_in[10];
  const float* Wn = (const float*)d_in[11]; const float* bn = (const float*)d_in[12];
  const float* Wc = (const float*)d_in[13]; const float* bc = (const float*)d_in[14];
  const float* Wf = (const float*)d_in[15]; const float* bf_ = (const float*)d_in[16];
  const float* Wi = (const float*)d_in[17]; const float* bi = (const float*)d_in[18];
  const float* Wg1 = (const float*)d_in[19]; const float* bg1 = (const float*)d_in[20];
  const float* Wg2 = (const float*)d_in[21]; const float* bg2 = (const float*)d_in[22];
  const float* Wo1 = (const float*)d_in[23]; const float* bo1 = (const float*)d_in[24];
  const float* Wo2 = (const float*)d_in[25]; const float* bo2 = (const float*)d_in[26];

  const int n = in_sizes[0] / 768;
  const int E = in_sizes[5] / 2;
  const int* srcp = eidx;
  const int* dstp = eidx + E;

  // ---- workspace layout (16B-aligned blocks first) ----
  float* bufA = (float*)d_ws;                       // n*128 floats
  float* bufB = bufA + (size_t)n*128;               // n*128 floats
  float* dis  = bufB + (size_t)n*128;               // n floats
  int*  cnt    = (int*)(dis + n);                   // n
  int*  rowptr = cnt + n;                           // n+1
  int*  cursor = rowptr + n + 1;                    // n
  int*  bsum   = cursor + n;                        // <=256
  int*  csr    = bsum + 256;                        // E

  const int gb1  = (n + 255)/256;
  const int gbe  = (E + 255)/256;
  const int grow = (n + 63)/64;
  const int nb   = (n + 1023)/1024;                 // scan blocks (<=256)
  const int gag  = (n + 3)/4;                       // gather: 4 nodes/block

  // ---- CSR build (shared by both GCN layers) ----
  hipMemsetAsync(cnt, 0, (size_t)n*sizeof(int), stream);
  k_hist <<<gbe, 256, 0, stream>>>(dstp, cnt, E);
  k_scan1<<<nb,  256, 0, stream>>>(cnt, rowptr, bsum, n);
  k_scan2<<<1,   256, 0, stream>>>(bsum, nb);
  k_scan3<<<gb1, 256, 0, stream>>>(rowptr, bsum, cnt, dis, cursor, n, E);
  k_fill <<<gbe, 256, 0, stream>>>(srcp, dstp, cursor, csr, E);

  // ---- encoders + concat + W_in ----
  k_encoder<<<grow, 256, 0, stream>>>(des,tweet,nump,catp,nfp,
      Wd,bd, Wt,bt, Wn,bn, Wc,bc, Wf,bf_, Wi,bi, bufA, n);

  // ---- GCN layer 1: y' = (x @ Wg1)*dis ; out = dis*(self+neigh sum) + bg1 ----
  k_gemm128<0,0,1><<<grow, 256, 0, stream>>>(bufA, Wg1, nullptr, bufB, nullptr, nullptr, dis, n);
  k_gather<<<gag, 256, 0, stream>>>(bufB, rowptr, csr, dis, bg1, bufA, n);

  // ---- GCN layer 2 ----
  k_gemm128<0,0,1><<<grow, 256, 0, stream>>>(bufA, Wg2, nullptr, bufB, nullptr, nullptr, dis, n);
  k_gather<<<gag, 256, 0, stream>>>(bufB, rowptr, csr, dis, bg2, bufA, n);

  // ---- head ----
  k_gemm128<1,1,0><<<grow, 256, 0, stream>>>(bufA, Wo1, bo1, (float*)d_out, Wo2, bo2, nullptr, n);
}

// Round 5
// 1853.595 us; speedup vs baseline: 3.7783x; 1.0320x over previous
//
#include <hip/hip_runtime.h>

static __device__ __forceinline__ float lrelu(float x){ return x > 0.f ? x : 0.01f*x; }

// ================= CSR build =================
__global__ __launch_bounds__(256) void k_hist(const int* __restrict__ dst, int* __restrict__ cnt, int E){
  int e = blockIdx.x*256 + threadIdx.x;
  if (e < E) atomicAdd(&cnt[dst[e]], 1);
}
__global__ __launch_bounds__(256) void k_scan1(const int* __restrict__ cnt, int* __restrict__ rowptr,
                                               int* __restrict__ bsum, int n){
  __shared__ int sh[256];
  const int t = threadIdx.x;
  const int base = blockIdx.x*1024 + t*4;
  int v0 = (base+0<n)? cnt[base+0]:0;
  int v1 = (base+1<n)? cnt[base+1]:0;
  int v2 = (base+2<n)? cnt[base+2]:0;
  int v3 = (base+3<n)? cnt[base+3]:0;
  int s = v0+v1+v2+v3;
  sh[t] = s; __syncthreads();
  #pragma unroll
  for (int off=1; off<256; off<<=1){
    int u = (t>=off)? sh[t-off] : 0;
    __syncthreads();
    sh[t] += u;
    __syncthreads();
  }
  int ex = sh[t] - s;
  if (base+0<n) rowptr[base+0] = ex;
  if (base+1<n) rowptr[base+1] = ex+v0;
  if (base+2<n) rowptr[base+2] = ex+v0+v1;
  if (base+3<n) rowptr[base+3] = ex+v0+v1+v2;
  if (t==255) bsum[blockIdx.x] = sh[255];
}
__global__ __launch_bounds__(256) void k_scan2(int* __restrict__ bsum, int nb){
  __shared__ int sh[256];
  const int t = threadIdx.x;
  int s = (t<nb)? bsum[t] : 0;
  sh[t] = s; __syncthreads();
  #pragma unroll
  for (int off=1; off<256; off<<=1){
    int u = (t>=off)? sh[t-off] : 0;
    __syncthreads();
    sh[t] += u;
    __syncthreads();
  }
  if (t<nb) bsum[t] = sh[t] - s;
}
__global__ __launch_bounds__(256) void k_scan3(int* __restrict__ rowptr, const int* __restrict__ bsum,
                                               const int* __restrict__ cnt, float* __restrict__ dis,
                                               int* __restrict__ cursor, int n, int E){
  int i = blockIdx.x*256 + threadIdx.x;
  if (i < n){
    int r = rowptr[i] + bsum[i>>10];
    rowptr[i] = r;
    cursor[i] = r;
    dis[i] = rsqrtf((float)cnt[i] + 1.0f);
  }
  if (i==0) rowptr[n] = E;
}
__global__ __launch_bounds__(256) void k_fill(const int* __restrict__ src, const int* __restrict__ dst,
                                              int* __restrict__ cursor, int* __restrict__ csr, int E){
  int e = blockIdx.x*256 + threadIdx.x;
  if (e < E){
    int pos = atomicAdd(&cursor[dst[e]], 1);
    csr[pos] = src[e];
  }
}

// ================= pull aggregation =================
__global__ __launch_bounds__(256) void k_gather(
    const float* __restrict__ yp, const int* __restrict__ rowptr,
    const int* __restrict__ csr, const float* __restrict__ dis,
    const float* __restrict__ bias, float* __restrict__ out, int n)
{
  int node = blockIdx.x*4 + (threadIdx.x>>6);
  if (node >= n) return;
  const int lane = threadIdx.x & 63;
  float2 acc = *(const float2*)(yp + (size_t)node*128 + lane*2);
  int j = rowptr[node], end = rowptr[node+1];
  for (; j+4<=end; j+=4){
    int s0=csr[j], s1=csr[j+1], s2=csr[j+2], s3=csr[j+3];
    float2 v0 = *(const float2*)(yp + (size_t)s0*128 + lane*2);
    float2 v1 = *(const float2*)(yp + (size_t)s1*128 + lane*2);
    float2 v2 = *(const float2*)(yp + (size_t)s2*128 + lane*2);
    float2 v3 = *(const float2*)(yp + (size_t)s3*128 + lane*2);
    acc.x += (v0.x+v1.x) + (v2.x+v3.x);
    acc.y += (v0.y+v1.y) + (v2.y+v3.y);
  }
  for (; j<end; ++j){
    int s = csr[j];
    float2 v = *(const float2*)(yp + (size_t)s*128 + lane*2);
    acc.x += v.x; acc.y += v.y;
  }
  float dd = dis[node];
  float2 b = *(const float2*)(bias + lane*2);
  float2 o = { acc.x*dd + b.x, acc.y*dd + b.y };
  *(float2*)(out + (size_t)node*128 + lane*2) = o;
}

// ================= skinny 768->NC encoder GEMM (high occupancy) =================
// xc layout: [n][64]; this kernel writes cols [col_off, col_off+NC)
template<int CP>
__global__ __launch_bounds__(256) void k_enc768(
    const float* __restrict__ X, const float* __restrict__ W, const float* __restrict__ b,
    float* __restrict__ xc, int col_off, int n)
{
  constexpr int NC = CP*4;
  __shared__ float xt[64][65];      // [k][row], conflict-free compute reads
  __shared__ float wt[64][NC];
  const int tid = threadIdx.x;
  const int r = tid & 63, cg = tid >> 6;
  const int row0 = blockIdx.x * 64;

  float acc[CP];
  #pragma unroll
  for (int j=0;j<CP;++j) acc[j]=0.f;

  for (int kt=0; kt<12; ++kt){
    __syncthreads();
    #pragma unroll
    for (int it=0; it<4; ++it){               // 64 rows x 64 k, transposed store
      int f = tid + it*256;
      int rr = f >> 4, k4 = f & 15;
      float4 v = make_float4(0.f,0.f,0.f,0.f);
      if (row0 + rr < n) v = *(const float4*)(X + (size_t)(row0+rr)*768 + kt*64 + k4*4);
      xt[k4*4+0][rr]=v.x; xt[k4*4+1][rr]=v.y; xt[k4*4+2][rr]=v.z; xt[k4*4+3][rr]=v.w;
    }
    for (int idx = tid; idx < 64*NC; idx += 256){
      int k = idx / NC, j = idx % NC;
      wt[k][j] = W[(size_t)(kt*64+k)*NC + j];
    }
    __syncthreads();
    #pragma unroll 8
    for (int k=0;k<64;++k){
      float xv = xt[k][r];
      #pragma unroll
      for (int j=0;j<CP;++j) acc[j] += xv * wt[k][cg*CP + j];
    }
  }
  if (row0 + r < n){
    #pragma unroll
    for (int j=0;j<CP;++j){
      int c = cg*CP + j;
      xc[(size_t)(row0+r)*64 + col_off + c] = lrelu(acc[j] + b[c]);
    }
  }
}

// ================= small encoders (direct global reads) =================
template<int K, int CP>
__device__ __forceinline__ void enc_small(
    const float* __restrict__ X, const float* __restrict__ W, const float* __restrict__ b,
    float (*xs)[132], int col_off, int row0, int n, int tid)
{
  const int r = tid & 63, cg = tid >> 6;
  const int NC = CP*4;
  float xr[K];
  #pragma unroll
  for (int k=0;k<K;++k) xr[k] = (row0 + r < n) ? X[(size_t)(row0+r)*K + k] : 0.f;
  #pragma unroll
  for (int j=0;j<CP;++j){
    int c = cg*CP + j;
    float a = b[c];
    #pragma unroll
    for (int k=0;k<K;++k) a += xr[k]*W[k*NC + c];
    xs[r][col_off + c] = lrelu(a);
  }
}

// ================= final encoder stage: xcat assembly + W_in GEMM =================
__global__ __launch_bounds__(256) void k_enc_final(
    const float* __restrict__ xc,
    const float* __restrict__ nump, const float* __restrict__ catp, const float* __restrict__ nfp,
    const float* __restrict__ Wn, const float* __restrict__ bn,
    const float* __restrict__ Wc, const float* __restrict__ bc,
    const float* __restrict__ Wf, const float* __restrict__ bf_,
    const float* __restrict__ Wi, const float* __restrict__ bi,
    float* __restrict__ x0, int n)
{
  __shared__ float xs[64][132];
  __shared__ float win[32][128];
  const int tid = threadIdx.x;
  const int row0 = blockIdx.x * 64;

  // cols 0:64 from xc (L2/L3-warm)
  #pragma unroll
  for (int it=0; it<4; ++it){
    int f = tid + it*256;
    int r = f >> 4, c4 = f & 15;
    float4 v = make_float4(0.f,0.f,0.f,0.f);
    if (row0 + r < n) v = *(const float4*)(xc + (size_t)(row0+r)*64 + c4*4);
    *(float4*)(&xs[r][c4*4]) = v;
  }
  // cols 64:128 computed in-place
  enc_small<7,3>(nump,  Wn, bn, xs, 64,  row0, n, tid);
  enc_small<11,10>(catp, Wc, bc, xs, 76, row0, n, tid);
  enc_small<1,3>(nfp,   Wf, bf_, xs, 116, row0, n, tid);

  const int tc = tid & 15, tr = tid >> 4;
  float a2[4][8];
  #pragma unroll
  for (int r=0;r<4;++r)
    #pragma unroll
    for (int c=0;c<8;++c) a2[r][c]=0.f;

  for (int kt=0; kt<4; ++kt){
    __syncthreads();
    #pragma unroll
    for (int it=0;it<4;++it){
      int f = tid + it*256;
      int rk = f >> 5, c4 = f & 31;
      *(float4*)(&win[rk][c4*4]) = *(const float4*)(Wi + (size_t)(kt*32+rk)*128 + c4*4);
    }
    __syncthreads();
    #pragma unroll 4
    for (int k=0;k<32;++k){
      float av[4];
      #pragma unroll
      for (int rr=0;rr<4;++rr) av[rr] = xs[tr*4+rr][kt*32+k];
      float4 w0 = *(const float4*)(&win[k][tc*8]);
      float4 w1 = *(const float4*)(&win[k][tc*8+4]);
      #pragma unroll
      for (int rr=0;rr<4;++rr){
        a2[rr][0] += av[rr]*w0.x; a2[rr][1] += av[rr]*w0.y;
        a2[rr][2] += av[rr]*w0.z; a2[rr][3] += av[rr]*w0.w;
        a2[rr][4] += av[rr]*w1.x; a2[rr][5] += av[rr]*w1.y;
        a2[rr][6] += av[rr]*w1.z; a2[rr][7] += av[rr]*w1.w;
      }
    }
  }
  float4 bv0 = *(const float4*)(bi + tc*8);
  float4 bv1 = *(const float4*)(bi + tc*8 + 4);
  #pragma unroll
  for (int rr=0;rr<4;++rr){
    int row = row0 + tr*4 + rr;
    if (row < n){
      float4 o0 = { lrelu(a2[rr][0]+bv0.x), lrelu(a2[rr][1]+bv0.y),
                    lrelu(a2[rr][2]+bv0.z), lrelu(a2[rr][3]+bv0.w) };
      float4 o1 = { lrelu(a2[rr][4]+bv1.x), lrelu(a2[rr][5]+bv1.y),
                    lrelu(a2[rr][6]+bv1.z), lrelu(a2[rr][7]+bv1.w) };
      *(float4*)(x0 + (size_t)row*128 + tc*8)     = o0;
      *(float4*)(x0 + (size_t)row*128 + tc*8 + 4) = o1;
    }
  }
}

// ================= 128x128 GEMM =================
template<int ACT, int FINAL, int SCALE>
__global__ __launch_bounds__(256) void k_gemm128(
    const float* __restrict__ X, const float* __restrict__ W, const float* __restrict__ bias,
    float* __restrict__ Y, const float* __restrict__ W2, const float* __restrict__ b2,
    const float* __restrict__ scale, int n)
{
  __shared__ float xs[64][132];
  __shared__ float wt[32][128];
  const int tid = threadIdx.x;
  const int row0 = blockIdx.x * 64;

  #pragma unroll
  for (int it=0; it<8; ++it){
    int f = tid + it*256;
    int r = f >> 5, c4 = f & 31;
    float4 v = make_float4(0.f,0.f,0.f,0.f);
    if (row0 + r < n) v = *(const float4*)(X + (size_t)(row0+r)*128 + c4*4);
    *(float4*)(&xs[r][c4*4]) = v;
  }
  const int tc = tid & 15, tr = tid >> 4;
  float a2[4][8];
  #pragma unroll
  for (int r=0;r<4;++r)
    #pragma unroll
    for (int c=0;c<8;++c) a2[r][c]=0.f;

  for (int kt=0; kt<4; ++kt){
    __syncthreads();
    #pragma unroll
    for (int it=0;it<4;++it){
      int f = tid + it*256;
      int rk = f >> 5, c4 = f & 31;
      *(float4*)(&wt[rk][c4*4]) = *(const float4*)(W + (size_t)(kt*32+rk)*128 + c4*4);
    }
    __syncthreads();
    #pragma unroll 4
    for (int k=0;k<32;++k){
      float av[4];
      #pragma unroll
      for (int rr=0;rr<4;++rr) av[rr] = xs[tr*4+rr][kt*32+k];
      float4 w0 = *(const float4*)(&wt[k][tc*8]);
      float4 w1 = *(const float4*)(&wt[k][tc*8+4]);
      #pragma unroll
      for (int rr=0;rr<4;++rr){
        a2[rr][0] += av[rr]*w0.x; a2[rr][1] += av[rr]*w0.y;
        a2[rr][2] += av[rr]*w0.z; a2[rr][3] += av[rr]*w0.w;
        a2[rr][4] += av[rr]*w1.x; a2[rr][5] += av[rr]*w1.y;
        a2[rr][6] += av[rr]*w1.z; a2[rr][7] += av[rr]*w1.w;
      }
    }
  }

  float vv[4][8];
  #pragma unroll
  for (int rr=0;rr<4;++rr){
    #pragma unroll
    for (int cc=0;cc<8;++cc){
      float v = a2[rr][cc];
      if (ACT) { v += bias[tc*8+cc]; v = lrelu(v); }
      vv[rr][cc] = v;
    }
  }

  if (!FINAL){
    #pragma unroll
    for (int rr=0;rr<4;++rr){
      int row = row0 + tr*4 + rr;
      if (row < n){
        float s = SCALE ? scale[row] : 1.0f;
        float4 o0 = { vv[rr][0]*s, vv[rr][1]*s, vv[rr][2]*s, vv[rr][3]*s };
        float4 o1 = { vv[rr][4]*s, vv[rr][5]*s, vv[rr][6]*s, vv[rr][7]*s };
        *(float4*)(Y + (size_t)row*128 + tc*8)     = o0;
        *(float4*)(Y + (size_t)row*128 + tc*8 + 4) = o1;
      }
    }
  } else {
    __syncthreads();
    #pragma unroll
    for (int rr=0;rr<4;++rr)
      #pragma unroll
      for (int cc=0;cc<8;++cc) xs[tr*4+rr][tc*8+cc] = vv[rr][cc];
    __syncthreads();
    if (tid < 128){
      int r = tid & 63, j = tid >> 6;
      float a = b2[j];
      #pragma unroll 8
      for (int k=0;k<128;++k) a += xs[r][k]*W2[k*2 + j];
      int row = row0 + r;
      if (row < n) Y[(size_t)row*2 + j] = a;
    }
  }
}

extern "C" void kernel_launch(void* const* d_in, const int* in_sizes, int n_in,
                              void* d_out, int out_size, void* d_ws, size_t ws_size,
                              hipStream_t stream)
{
  (void)n_in; (void)out_size; (void)ws_size;
  const float* des   = (const float*)d_in[0];
  const float* tweet = (const float*)d_in[1];
  const float* nump  = (const float*)d_in[2];
  const float* catp  = (const float*)d_in[3];
  const float* nfp   = (const float*)d_in[4];
  const int*   eidx  = (const int*)d_in[5];
  const float* Wd = (const float*)d_in[7];  const float* bd = (const float*)d_in[8];
  const float* Wt = (const float*)d_in[9];  const float* bt = (const float*)d_in[10];
  const float* Wn = (const float*)d_in[11]; const float* bn = (const float*)d_in[12];
  const float* Wc = (const float*)d_in[13]; const float* bc = (const float*)d_in[14];
  const float* Wf = (const float*)d_in[15]; const float* bf_ = (const float*)d_in[16];
  const float* Wi = (const float*)d_in[17]; const float* bi = (const float*)d_in[18];
  const float* Wg1 = (const float*)d_in[19]; const float* bg1 = (const float*)d_in[20];
  const float* Wg2 = (const float*)d_in[21]; const float* bg2 = (const float*)d_in[22];
  const float* Wo1 = (const float*)d_in[23]; const float* bo1 = (const float*)d_in[24];
  const float* Wo2 = (const float*)d_in[25]; const float* bo2 = (const float*)d_in[26];

  const int n = in_sizes[0] / 768;
  const int E = in_sizes[5] / 2;
  const int* srcp = eidx;
  const int* dstp = eidx + E;

  // ---- workspace layout ----
  float* bufA = (float*)d_ws;                       // n*128
  float* bufB = bufA + (size_t)n*128;               // n*128
  float* xc   = bufB + (size_t)n*128;               // n*64
  float* dis  = xc   + (size_t)n*64;                // n
  int*  cnt    = (int*)(dis + n);                   // n
  int*  rowptr = cnt + n;                           // n+1
  int*  cursor = rowptr + n + 1;                    // n
  int*  bsum   = cursor + n;                        // <=256
  int*  csr    = bsum + 256;                        // E

  const int gb1  = (n + 255)/256;
  const int gbe  = (E + 255)/256;
  const int grow = (n + 63)/64;
  const int nb   = (n + 1023)/1024;
  const int gag  = (n + 3)/4;

  // ---- CSR build ----
  hipMemsetAsync(cnt, 0, (size_t)n*sizeof(int), stream);
  k_hist <<<gbe, 256, 0, stream>>>(dstp, cnt, E);
  k_scan1<<<nb,  256, 0, stream>>>(cnt, rowptr, bsum, n);
  k_scan2<<<1,   256, 0, stream>>>(bsum, nb);
  k_scan3<<<gb1, 256, 0, stream>>>(rowptr, bsum, cnt, dis, cursor, n, E);
  k_fill <<<gbe, 256, 0, stream>>>(srcp, dstp, cursor, csr, E);

  // ---- encoder chain ----
  k_enc768<7><<<grow, 256, 0, stream>>>(des,   Wd, bd, xc, 0,  n);
  k_enc768<9><<<grow, 256, 0, stream>>>(tweet, Wt, bt, xc, 28, n);
  k_enc_final<<<grow, 256, 0, stream>>>(xc, nump, catp, nfp,
      Wn,bn, Wc,bc, Wf,bf_, Wi,bi, bufA, n);

  // ---- GCN layer 1 ----
  k_gemm128<0,0,1><<<grow, 256, 0, stream>>>(bufA, Wg1, nullptr, bufB, nullptr, nullptr, dis, n);
  k_gather<<<gag, 256, 0, stream>>>(bufB, rowptr, csr, dis, bg1, bufA, n);

  // ---- GCN layer 2 ----
  k_gemm128<0,0,1><<<grow, 256, 0, stream>>>(bufA, Wg2, nullptr, bufB, nullptr, nullptr, dis, n);
  k_gather<<<gag, 256, 0, stream>>>(bufB, rowptr, csr, dis, bg2, bufA, n);

  // ---- head ----
  k_gemm128<1,1,0><<<grow, 256, 0, stream>>>(bufA, Wo1, bo1, (float*)d_out, Wo2, bo2, nullptr, n);
}